// Round 8
// baseline (60.510 us; speedup 1.0000x reference)
//
#include <hip/hip_runtime.h>
#include <math.h>
#include <stdint.h>

#define CH 16
#define DIM 8
#define ROW 128            // CH*DIM
#define TILE_ROWS 32       // smaller tiles -> 2048 blocks -> generational churn
#define TPB 2              // tiles per block, both prefetched into registers
#define BLK 256            // 4 waves

typedef __attribute__((ext_vector_type(8))) short bf16x8;
typedef __attribute__((ext_vector_type(4))) float f32x4;
typedef __attribute__((ext_vector_type(4))) unsigned int u32x4;

// Cayley sign for Cl(3,0): e_a * e_b = csign(a,b) * e_{a^b}
__device__ __forceinline__ float csign(int a, int b) {
    int s = 0;
    int aa = a >> 1;
    while (aa) { s ^= (__popc(aa & b) & 1); aa >>= 1; }
    return s ? -1.0f : 1.0f;
}

// float -> bf16 (round-to-nearest-even)
__device__ __forceinline__ unsigned short f2bf(float f) {
    union { float f; unsigned u; } x; x.f = f;
    unsigned r = x.u + 0x7FFF + ((x.u >> 16) & 1);
    return (unsigned short)(r >> 16);
}

// Exact-GELU via odd Taylor poly for erf. Domain: LN gives |mv|=1 per channel,
// rotor sandwich is orthogonal in Cl(3,0), ln_scale folded into D ->
// |s| <= ~1.02 -> |z| <= 0.73; erf poly err < 2e-6 there.
__device__ __forceinline__ float gelu_poly(float s) {
    const float z = s * 0.70710678f;
    const float u = z * z;
    float p = -8.5483270e-04f;
    p = fmaf(p, u,  5.2239776e-03f);
    p = fmaf(p, u, -2.6866138e-02f);
    p = fmaf(p, u,  1.1283792e-01f);
    p = fmaf(p, u, -3.7612639e-01f);
    p = fmaf(p, u,  1.1283792e+00f);
    return 0.5f * s * fmaf(z, p, 1.0f);
}

// barrier draining only LDS ordering (keeps global loads/stores in flight)
__device__ __forceinline__ void barrier_lgkm() {
    asm volatile("s_waitcnt lgkmcnt(0)" ::: "memory");
    __builtin_amdgcn_s_barrier();
    __builtin_amdgcn_sched_barrier(0);
}

// ---------------------------------------------------------------------------
// Precompute, grid=2 x 1024 threads:
//   block 0: D[f_out][f_in] bf16 block-diag rotor-sandwich (ln_scale folded)
//   block 1: W2R[out_f][in_f] bf16 128x128 CliffordLinear matrix
// ws as ushort*: u[0..16384) = D, u[16384..32768) = W2R
// ---------------------------------------------------------------------------
__global__ void precompute_kernel(const float* __restrict__ rotor,
                                  const float* __restrict__ w,
                                  const float* __restrict__ ln_scale,
                                  float* __restrict__ ws)
{
    const int t = threadIdx.x;
    unsigned short* D   = (unsigned short*)ws;
    unsigned short* w2r = D + 16384;

    if (blockIdx.x == 0) {
        // zero D: 32 KiB = 2048 x 16B
        ((u32x4*)D)[t]        = (u32x4){0u, 0u, 0u, 0u};
        ((u32x4*)D)[t + 1024] = (u32x4){0u, 0u, 0u, 0u};
        __syncthreads();

        if (t < CH) {
            const int c = t;
            float r[8];
            float nn = 0.f;
            #pragma unroll
            for (int i = 0; i < 8; ++i) { r[i] = rotor[c * 8 + i]; nn += r[i] * r[i]; }
            const float inv = rsqrtf(nn + 1e-6f);
            #pragma unroll
            for (int i = 0; i < 8; ++i) r[i] *= inv;

            const float REVv[8] = {1.f, 1.f, 1.f, -1.f, 1.f, -1.f, -1.f, -1.f};
            float rr[8];
            #pragma unroll
            for (int j = 0; j < 8; ++j) rr[j] = r[j] * REVv[j];

            float L[8][8], R[8][8];
            #pragma unroll
            for (int a = 0; a < 8; ++a)
                #pragma unroll
                for (int b = 0; b < 8; ++b) { L[a][b] = 0.f; R[a][b] = 0.f; }

            #pragma unroll
            for (int i = 0; i < 8; ++i)
                #pragma unroll
                for (int j = 0; j < 8; ++j) {
                    const float s = csign(i, j);
                    L[i ^ j][j] += r[i] * s;
                    R[i ^ j][i] += rr[j] * s;
                }

            const float sc = ln_scale[c];
            #pragma unroll
            for (int k = 0; k < 8; ++k)
                #pragma unroll
                for (int m = 0; m < 8; ++m) {
                    float acc = 0.f;
                    #pragma unroll
                    for (int i = 0; i < 8; ++i) acc += R[k][i] * L[i][m];
                    D[(c * 8 + k) * ROW + (c * 8 + m)] = f2bf(acc * sc);
                }
        }
    } else {
        // W2R: 2048 rows of 16B, 1024 threads x 2
        #pragma unroll
        for (int task = t; task < ROW * CH; task += 1024) {
            const int outf = task >> 4;
            const int ci   = task & 15;
            const int kb = outf & 7, o = outf >> 3;
            const float4 w0 = *(const float4*)(w + (o * CH + ci) * 8);
            const float4 w1 = *(const float4*)(w + (o * CH + ci) * 8 + 4);
            const float wv[8] = {w0.x, w0.y, w0.z, w0.w, w1.x, w1.y, w1.z, w1.w};
            bf16x8 pk;
            #pragma unroll
            for (int j = 0; j < 8; ++j) {
                const int i = kb ^ j;
                pk[j] = (short)f2bf(wv[i] * csign(i, j));
            }
            *(bf16x8*)(w2r + outf * ROW + ci * 8) = pk;
        }
    }
}

// ---------------------------------------------------------------------------
// Fused kernel helpers
// ---------------------------------------------------------------------------

// LN -> rotor-sandwich MFMA (block-diag D) -> GELU -> swizzled bf16 sG write
__device__ __forceinline__ void phase1_mv(const float4 a, const float4 b,
                                          const bf16x8* Df, unsigned short* sG,
                                          int wave, int lcol, int lkg, int rt) {
    const float nn = a.x*a.x + a.y*a.y + a.z*a.z + a.w*a.w
                   + b.x*b.x + b.y*b.y + b.z*b.z + b.w*b.w;
    const float inv = rsqrtf(nn + 1e-6f);
    bf16x8 af;
    af[0] = (short)f2bf(a.x * inv); af[1] = (short)f2bf(a.y * inv);
    af[2] = (short)f2bf(a.z * inv); af[3] = (short)f2bf(a.w * inv);
    af[4] = (short)f2bf(b.x * inv); af[5] = (short)f2bf(b.y * inv);
    af[6] = (short)f2bf(b.z * inv); af[7] = (short)f2bf(b.w * inv);

    f32x4 p0 = (f32x4){0.f, 0.f, 0.f, 0.f};
    f32x4 p1 = (f32x4){0.f, 0.f, 0.f, 0.f};
    p0 = __builtin_amdgcn_mfma_f32_16x16x32_bf16(af, Df[0], p0, 0, 0, 0);
    p1 = __builtin_amdgcn_mfma_f32_16x16x32_bf16(af, Df[1], p1, 0, 0, 0);

    #pragma unroll
    for (int ctl = 0; ctl < 2; ++ctl) {
        const f32x4 p = ctl ? p1 : p0;
        const int colg = (2 * wave + ctl) * 16 + lcol;
        #pragma unroll
        for (int j = 0; j < 4; ++j) {
            const float y = gelu_poly(p[j]);
            const int row   = rt * 16 + lkg * 4 + j;
            const int chunk = (colg >> 3) ^ (row & 15);
            sG[row * ROW + chunk * 8 + (colg & 7)] = f2bf(y);
        }
    }
}

// 32x32 output sub-tile per wave: g(sG) @ W2R^T, store per rt (early reg free)
__device__ __forceinline__ void gemm_store_tile(const unsigned short* sG,
                                                const bf16x8 Bf[2][4],
                                                float* out, size_t trow0,
                                                int colb, int lcol, int lkg,
                                                const float bv[2]) {
    #pragma unroll
    for (int rt = 0; rt < 2; ++rt) {
        f32x4 acc[2];
        acc[0] = (f32x4){0.f, 0.f, 0.f, 0.f};
        acc[1] = (f32x4){0.f, 0.f, 0.f, 0.f};
        const int row = rt * 16 + lcol;
        #pragma unroll
        for (int ks = 0; ks < 4; ++ks) {
            const int chunk = (ks * 4 + lkg) ^ (row & 15);
            const bf16x8 afr = *(const bf16x8*)(sG + row * ROW + chunk * 8);
            acc[0] = __builtin_amdgcn_mfma_f32_16x16x32_bf16(
                         afr, Bf[0][ks], acc[0], 0, 0, 0);
            acc[1] = __builtin_amdgcn_mfma_f32_16x16x32_bf16(
                         afr, Bf[1][ks], acc[1], 0, 0, 0);
        }
        // store this rt immediately (nontemporal: write-once stream, skip L2
        // partial-line dirty eviction = suspected WRITE_SIZE 90 vs 64 MB gap)
        const size_t rbase = trow0 + rt * 16 + lkg * 4;
        #pragma unroll
        for (int j = 0; j < 4; ++j) {
            #pragma unroll
            for (int ct = 0; ct < 2; ++ct) {
                const int col = colb + ct * 16 + lcol;
                __builtin_nontemporal_store(acc[ct][j] + bv[ct],
                                            out + (rbase + j) * ROW + col);
            }
        }
    }
}

// ---------------------------------------------------------------------------
// Fused: 2 x 32-row tiles per block, both x tiles register-prefetched at
// block start. sG ping-pong -> ONE barrier per tile. grid = 2048 blocks:
// more than resident capacity -> generational churn staggers loads vs stores
// (R7 lesson: grid == capacity -> lockstep + exposed 5us store tail).
// launch_bounds(256,5): VGPR cap 102, live-set peak ~92 -> 5 blocks/CU.
// ---------------------------------------------------------------------------
__global__ __launch_bounds__(BLK, 5) void fused_kernel(
        const float* __restrict__ x,
        const float* __restrict__ bias,
        const float* __restrict__ ws,
        float* __restrict__ out)
{
    __shared__ unsigned short sG[2][TILE_ROWS * ROW];   // 2 x 8 KiB

    const int t    = threadIdx.x;
    const int lane = t & 63;
    const int wave = t >> 6;
    const int lcol = lane & 15;
    const int lkg  = lane >> 4;
    const int c    = 4 * wave + lkg;

    const unsigned short* D   = (const unsigned short*)ws;
    const unsigned short* w2r = D + 16384;

    const size_t row0 = (size_t)blockIdx.x * (TPB * TILE_ROWS);

    // ---- tile0 x -> regs (oldest in vmcnt FIFO)
    float4 xa0[2], xb0[2];
    #pragma unroll
    for (int rt = 0; rt < 2; ++rt) {
        const float4* xp = (const float4*)(x + ((row0 + rt * 16 + lcol) * CH + c) * DIM);
        xa0[rt] = xp[0];
        xb0[rt] = xp[1];
    }

    // ---- D / W2R fragments + bias
    bf16x8 Df[2];
    #pragma unroll
    for (int ctl = 0; ctl < 2; ++ctl) {
        const int col = (2 * wave + ctl) * 16 + lcol;
        Df[ctl] = *(const bf16x8*)(D + col * ROW + 32 * wave + lkg * 8);
    }
    const int colb = wave * 32;
    bf16x8 Bf[2][4];
    #pragma unroll
    for (int ct = 0; ct < 2; ++ct)
        #pragma unroll
        for (int ks = 0; ks < 4; ++ks) {
            const int col = colb + ct * 16 + lcol;
            Bf[ct][ks] = *(const bf16x8*)(w2r + col * ROW + ks * 32 + lkg * 8);
        }
    float bv[2];
    bv[0] = bias[colb + lcol];
    bv[1] = bias[colb + 16 + lcol];

    // ---- tile1 x -> regs (newest; stays in flight through tile0 compute)
    float4 xa1[2], xb1[2];
    #pragma unroll
    for (int rt = 0; rt < 2; ++rt) {
        const float4* xp = (const float4*)(x + ((row0 + TILE_ROWS + rt * 16 + lcol) * CH + c) * DIM);
        xa1[rt] = xp[0];
        xb1[rt] = xp[1];
    }

    // ---- tile 0
    #pragma unroll
    for (int rt = 0; rt < 2; ++rt)
        phase1_mv(xa0[rt], xb0[rt], Df, sG[0], wave, lcol, lkg, rt);

    barrier_lgkm();                       // sG[0] visible; tile1 loads in flight

    gemm_store_tile(sG[0], Bf, out, row0, colb, lcol, lkg, bv);

    // ---- tile 1 (writes sG[1]: no barrier needed against sG[0] readers)
    #pragma unroll
    for (int rt = 0; rt < 2; ++rt)
        phase1_mv(xa1[rt], xb1[rt], Df, sG[1], wave, lcol, lkg, rt);

    barrier_lgkm();

    gemm_store_tile(sG[1], Bf, out, row0 + TILE_ROWS, colb, lcol, lkg, bv);
}

extern "C" void kernel_launch(void* const* d_in, const int* in_sizes, int n_in,
                              void* d_out, int out_size, void* d_ws, size_t ws_size,
                              hipStream_t stream)
{
    const float* x        = (const float*)d_in[0];
    const float* ln_scale = (const float*)d_in[1];
    const float* rotor    = (const float*)d_in[2];
    const float* w        = (const float*)d_in[3];
    const float* bias     = (const float*)d_in[4];
    float* out = (float*)d_out;
    float* ws  = (float*)d_ws;

    precompute_kernel<<<dim3(2), dim3(1024), 0, stream>>>(rotor, w, ln_scale, ws);

    const int nrows   = in_sizes[0] / (CH * DIM);          // 131072
    const int nblocks = nrows / (TPB * TILE_ROWS);         // 2048

    fused_kernel<<<dim3(nblocks), dim3(BLK), 0, stream>>>(x, bias, ws, out);
}

// Round 9
// 38.551 us; speedup vs baseline: 1.5696x; 1.5696x over previous
//
#include <hip/hip_runtime.h>
#include <math.h>
#include <stdint.h>

#define CH 16
#define DIM 8
#define ROW 128            // CH*DIM
#define TILE_ROWS 32       // grid=2048: resident 5/CU + queued -> churn
#define TPB 2              // tiles per block, both prefetched into registers
#define BLK 256            // 4 waves

typedef __attribute__((ext_vector_type(8))) short bf16x8;
typedef __attribute__((ext_vector_type(4))) float f32x4;
typedef __attribute__((ext_vector_type(4))) unsigned int u32x4;

// Cayley sign for Cl(3,0): e_a * e_b = csign(a,b) * e_{a^b}
__device__ __forceinline__ float csign(int a, int b) {
    int s = 0;
    int aa = a >> 1;
    while (aa) { s ^= (__popc(aa & b) & 1); aa >>= 1; }
    return s ? -1.0f : 1.0f;
}

// float -> bf16 (round-to-nearest-even)
__device__ __forceinline__ unsigned short f2bf(float f) {
    union { float f; unsigned u; } x; x.f = f;
    unsigned r = x.u + 0x7FFF + ((x.u >> 16) & 1);
    return (unsigned short)(r >> 16);
}

// Exact-GELU via odd Taylor poly for erf (|s|<=~1.02 after unit-norm rotor
// sandwich; poly err < 2e-6 on that domain).
__device__ __forceinline__ float gelu_poly(float s) {
    const float z = s * 0.70710678f;
    const float u = z * z;
    float p = -8.5483270e-04f;
    p = fmaf(p, u,  5.2239776e-03f);
    p = fmaf(p, u, -2.6866138e-02f);
    p = fmaf(p, u,  1.1283792e-01f);
    p = fmaf(p, u, -3.7612639e-01f);
    p = fmaf(p, u,  1.1283792e+00f);
    return 0.5f * s * fmaf(z, p, 1.0f);
}

// barrier draining only LDS ordering (keeps global loads/stores in flight)
__device__ __forceinline__ void barrier_lgkm() {
    asm volatile("s_waitcnt lgkmcnt(0)" ::: "memory");
    __builtin_amdgcn_s_barrier();
    __builtin_amdgcn_sched_barrier(0);
}

// ---------------------------------------------------------------------------
// Precompute, grid=2 x 1024 threads:
//   block 0: D[f_out][f_in] bf16 block-diag rotor-sandwich (ln_scale folded)
//   block 1: W2R[out_f][in_f] bf16 128x128 CliffordLinear matrix
// ws as ushort*: u[0..16384) = D, u[16384..32768) = W2R
// ---------------------------------------------------------------------------
__global__ void precompute_kernel(const float* __restrict__ rotor,
                                  const float* __restrict__ w,
                                  const float* __restrict__ ln_scale,
                                  float* __restrict__ ws)
{
    const int t = threadIdx.x;
    unsigned short* D   = (unsigned short*)ws;
    unsigned short* w2r = D + 16384;

    if (blockIdx.x == 0) {
        ((u32x4*)D)[t]        = (u32x4){0u, 0u, 0u, 0u};
        ((u32x4*)D)[t + 1024] = (u32x4){0u, 0u, 0u, 0u};
        __syncthreads();

        if (t < CH) {
            const int c = t;
            float r[8];
            float nn = 0.f;
            #pragma unroll
            for (int i = 0; i < 8; ++i) { r[i] = rotor[c * 8 + i]; nn += r[i] * r[i]; }
            const float inv = rsqrtf(nn + 1e-6f);
            #pragma unroll
            for (int i = 0; i < 8; ++i) r[i] *= inv;

            const float REVv[8] = {1.f, 1.f, 1.f, -1.f, 1.f, -1.f, -1.f, -1.f};
            float rr[8];
            #pragma unroll
            for (int j = 0; j < 8; ++j) rr[j] = r[j] * REVv[j];

            float L[8][8], R[8][8];
            #pragma unroll
            for (int a = 0; a < 8; ++a)
                #pragma unroll
                for (int b = 0; b < 8; ++b) { L[a][b] = 0.f; R[a][b] = 0.f; }

            #pragma unroll
            for (int i = 0; i < 8; ++i)
                #pragma unroll
                for (int j = 0; j < 8; ++j) {
                    const float s = csign(i, j);
                    L[i ^ j][j] += r[i] * s;
                    R[i ^ j][i] += rr[j] * s;
                }

            const float sc = ln_scale[c];
            #pragma unroll
            for (int k = 0; k < 8; ++k)
                #pragma unroll
                for (int m = 0; m < 8; ++m) {
                    float acc = 0.f;
                    #pragma unroll
                    for (int i = 0; i < 8; ++i) acc += R[k][i] * L[i][m];
                    D[(c * 8 + k) * ROW + (c * 8 + m)] = f2bf(acc * sc);
                }
        }
    } else {
        #pragma unroll
        for (int task = t; task < ROW * CH; task += 1024) {
            const int outf = task >> 4;
            const int ci   = task & 15;
            const int kb = outf & 7, o = outf >> 3;
            const float4 w0 = *(const float4*)(w + (o * CH + ci) * 8);
            const float4 w1 = *(const float4*)(w + (o * CH + ci) * 8 + 4);
            const float wv[8] = {w0.x, w0.y, w0.z, w0.w, w1.x, w1.y, w1.z, w1.w};
            bf16x8 pk;
            #pragma unroll
            for (int j = 0; j < 8; ++j) {
                const int i = kb ^ j;
                pk[j] = (short)f2bf(wv[i] * csign(i, j));
            }
            *(bf16x8*)(w2r + outf * ROW + ci * 8) = pk;
        }
    }
}

// ---------------------------------------------------------------------------
// Fused kernel helpers
// ---------------------------------------------------------------------------

// LN -> rotor-sandwich MFMA (block-diag D) -> GELU -> swizzled bf16 sG write
__device__ __forceinline__ void phase1_mv(const float4 a, const float4 b,
                                          const bf16x8* Df, unsigned short* sG,
                                          int wave, int lcol, int lkg, int rt) {
    const float nn = a.x*a.x + a.y*a.y + a.z*a.z + a.w*a.w
                   + b.x*b.x + b.y*b.y + b.z*b.z + b.w*b.w;
    const float inv = rsqrtf(nn + 1e-6f);
    bf16x8 af;
    af[0] = (short)f2bf(a.x * inv); af[1] = (short)f2bf(a.y * inv);
    af[2] = (short)f2bf(a.z * inv); af[3] = (short)f2bf(a.w * inv);
    af[4] = (short)f2bf(b.x * inv); af[5] = (short)f2bf(b.y * inv);
    af[6] = (short)f2bf(b.z * inv); af[7] = (short)f2bf(b.w * inv);

    f32x4 p0 = (f32x4){0.f, 0.f, 0.f, 0.f};
    f32x4 p1 = (f32x4){0.f, 0.f, 0.f, 0.f};
    p0 = __builtin_amdgcn_mfma_f32_16x16x32_bf16(af, Df[0], p0, 0, 0, 0);
    p1 = __builtin_amdgcn_mfma_f32_16x16x32_bf16(af, Df[1], p1, 0, 0, 0);

    #pragma unroll
    for (int ctl = 0; ctl < 2; ++ctl) {
        const f32x4 p = ctl ? p1 : p0;
        const int colg = (2 * wave + ctl) * 16 + lcol;
        #pragma unroll
        for (int j = 0; j < 4; ++j) {
            const float y = gelu_poly(p[j]);
            const int row   = rt * 16 + lkg * 4 + j;
            const int chunk = (colg >> 3) ^ (row & 15);
            sG[row * ROW + chunk * 8 + (colg & 7)] = f2bf(y);
        }
    }
}

// 32x32 output sub-tile per wave: g(sG) @ W2R^T, per-rt nontemporal store
__device__ __forceinline__ void gemm_store_tile(const unsigned short* sG,
                                                const bf16x8 Bf[2][4],
                                                float* out, size_t trow0,
                                                int colb, int lcol, int lkg,
                                                const float bv[2]) {
    #pragma unroll
    for (int rt = 0; rt < 2; ++rt) {
        f32x4 acc[2];
        acc[0] = (f32x4){0.f, 0.f, 0.f, 0.f};
        acc[1] = (f32x4){0.f, 0.f, 0.f, 0.f};
        const int row = rt * 16 + lcol;
        #pragma unroll
        for (int ks = 0; ks < 4; ++ks) {
            const int chunk = (ks * 4 + lkg) ^ (row & 15);
            const bf16x8 afr = *(const bf16x8*)(sG + row * ROW + chunk * 8);
            acc[0] = __builtin_amdgcn_mfma_f32_16x16x32_bf16(
                         afr, Bf[0][ks], acc[0], 0, 0, 0);
            acc[1] = __builtin_amdgcn_mfma_f32_16x16x32_bf16(
                         afr, Bf[1][ks], acc[1], 0, 0, 0);
        }
        const size_t rbase = trow0 + rt * 16 + lkg * 4;
        #pragma unroll
        for (int j = 0; j < 4; ++j) {
            #pragma unroll
            for (int ct = 0; ct < 2; ++ct) {
                const int col = colb + ct * 16 + lcol;
                __builtin_nontemporal_store(acc[ct][j] + bv[ct],
                                            out + (rbase + j) * ROW + col);
            }
        }
    }
}

// ---------------------------------------------------------------------------
// Fused: 2 x 32-row tiles per block, both x tiles register-prefetched at
// block start. sG ping-pong -> ONE barrier per tile. grid = 2048 blocks,
// resident ~5/CU (VGPR ~100) -> second generation overlaps store tails.
// launch_bounds(256,4): VGPR cap 128. R3+R8 lesson (twice burned): never
// force >4 waves/EU here -- allocator spills catastrophically.
// ---------------------------------------------------------------------------
__global__ __launch_bounds__(BLK, 4) void fused_kernel(
        const float* __restrict__ x,
        const float* __restrict__ bias,
        const float* __restrict__ ws,
        float* __restrict__ out)
{
    __shared__ unsigned short sG[2][TILE_ROWS * ROW];   // 2 x 8 KiB

    const int t    = threadIdx.x;
    const int lane = t & 63;
    const int wave = t >> 6;
    const int lcol = lane & 15;
    const int lkg  = lane >> 4;
    const int c    = 4 * wave + lkg;

    const unsigned short* D   = (const unsigned short*)ws;
    const unsigned short* w2r = D + 16384;

    const size_t row0 = (size_t)blockIdx.x * (TPB * TILE_ROWS);

    // ---- tile0 x -> regs (oldest in vmcnt FIFO)
    float4 xa0[2], xb0[2];
    #pragma unroll
    for (int rt = 0; rt < 2; ++rt) {
        const float4* xp = (const float4*)(x + ((row0 + rt * 16 + lcol) * CH + c) * DIM);
        xa0[rt] = xp[0];
        xb0[rt] = xp[1];
    }

    // ---- D / W2R fragments + bias
    bf16x8 Df[2];
    #pragma unroll
    for (int ctl = 0; ctl < 2; ++ctl) {
        const int col = (2 * wave + ctl) * 16 + lcol;
        Df[ctl] = *(const bf16x8*)(D + col * ROW + 32 * wave + lkg * 8);
    }
    const int colb = wave * 32;
    bf16x8 Bf[2][4];
    #pragma unroll
    for (int ct = 0; ct < 2; ++ct)
        #pragma unroll
        for (int ks = 0; ks < 4; ++ks) {
            const int col = colb + ct * 16 + lcol;
            Bf[ct][ks] = *(const bf16x8*)(w2r + col * ROW + ks * 32 + lkg * 8);
        }
    float bv[2];
    bv[0] = bias[colb + lcol];
    bv[1] = bias[colb + 16 + lcol];

    // ---- tile1 x -> regs (newest; stays in flight through tile0 compute)
    float4 xa1[2], xb1[2];
    #pragma unroll
    for (int rt = 0; rt < 2; ++rt) {
        const float4* xp = (const float4*)(x + ((row0 + TILE_ROWS + rt * 16 + lcol) * CH + c) * DIM);
        xa1[rt] = xp[0];
        xb1[rt] = xp[1];
    }

    // ---- tile 0
    #pragma unroll
    for (int rt = 0; rt < 2; ++rt)
        phase1_mv(xa0[rt], xb0[rt], Df, sG[0], wave, lcol, lkg, rt);

    barrier_lgkm();                       // sG[0] visible; tile1 loads in flight

    gemm_store_tile(sG[0], Bf, out, row0, colb, lcol, lkg, bv);

    // ---- tile 1 (writes sG[1]: no barrier against sG[0] readers needed)
    #pragma unroll
    for (int rt = 0; rt < 2; ++rt)
        phase1_mv(xa1[rt], xb1[rt], Df, sG[1], wave, lcol, lkg, rt);

    barrier_lgkm();

    gemm_store_tile(sG[1], Bf, out, row0 + TILE_ROWS, colb, lcol, lkg, bv);
}

extern "C" void kernel_launch(void* const* d_in, const int* in_sizes, int n_in,
                              void* d_out, int out_size, void* d_ws, size_t ws_size,
                              hipStream_t stream)
{
    const float* x        = (const float*)d_in[0];
    const float* ln_scale = (const float*)d_in[1];
    const float* rotor    = (const float*)d_in[2];
    const float* w        = (const float*)d_in[3];
    const float* bias     = (const float*)d_in[4];
    float* out = (float*)d_out;
    float* ws  = (float*)d_ws;

    precompute_kernel<<<dim3(2), dim3(1024), 0, stream>>>(rotor, w, ln_scale, ws);

    const int nrows   = in_sizes[0] / (CH * DIM);          // 131072
    const int nblocks = nrows / (TPB * TILE_ROWS);         // 2048

    fused_kernel<<<dim3(nblocks), dim3(BLK), 0, stream>>>(x, bias, ws, out);
}

// Round 11
// 38.207 us; speedup vs baseline: 1.5837x; 1.0090x over previous
//
#include <hip/hip_runtime.h>
#include <math.h>
#include <stdint.h>

#define CH 16
#define DIM 8
#define ROW 128            // CH*DIM
#define TILE_ROWS 64
#define TPB 2              // tiles per block, both prefetched into registers
#define BLK 256            // 4 waves

typedef __attribute__((ext_vector_type(8))) short bf16x8;
typedef __attribute__((ext_vector_type(4))) float f32x4;
typedef __attribute__((ext_vector_type(4))) unsigned int u32x4;

// Cayley sign for Cl(3,0): e_a * e_b = csign(a,b) * e_{a^b}
__device__ __forceinline__ float csign(int a, int b) {
    int s = 0;
    int aa = a >> 1;
    while (aa) { s ^= (__popc(aa & b) & 1); aa >>= 1; }
    return s ? -1.0f : 1.0f;
}

// float -> bf16 (round-to-nearest-even)
__device__ __forceinline__ unsigned short f2bf(float f) {
    union { float f; unsigned u; } x; x.f = f;
    unsigned r = x.u + 0x7FFF + ((x.u >> 16) & 1);
    return (unsigned short)(r >> 16);
}

// Exact-GELU via odd Taylor poly for erf (|s|<=~1.02 after unit-norm rotor
// sandwich, ln_scale folded into D; poly err < 2e-6 on that domain).
__device__ __forceinline__ float gelu_poly(float s) {
    const float z = s * 0.70710678f;
    const float u = z * z;
    float p = -8.5483270e-04f;
    p = fmaf(p, u,  5.2239776e-03f);
    p = fmaf(p, u, -2.6866138e-02f);
    p = fmaf(p, u,  1.1283792e-01f);
    p = fmaf(p, u, -3.7612639e-01f);
    p = fmaf(p, u,  1.1283792e+00f);
    return 0.5f * s * fmaf(z, p, 1.0f);
}

// barrier draining only LDS ordering (keeps global loads/stores in flight)
__device__ __forceinline__ void barrier_lgkm() {
    asm volatile("s_waitcnt lgkmcnt(0)" ::: "memory");
    __builtin_amdgcn_s_barrier();
    __builtin_amdgcn_sched_barrier(0);
}

// ---------------------------------------------------------------------------
// Precompute, grid=2 x 1024 threads:
//   block 0: D[f_out][f_in] bf16 block-diag rotor-sandwich (ln_scale folded)
//   block 1: W2R[out_f][in_f] bf16 128x128 CliffordLinear matrix
// ws as ushort*: u[0..16384) = D, u[16384..32768) = W2R
// ---------------------------------------------------------------------------
__global__ void precompute_kernel(const float* __restrict__ rotor,
                                  const float* __restrict__ w,
                                  const float* __restrict__ ln_scale,
                                  float* __restrict__ ws)
{
    const int t = threadIdx.x;
    unsigned short* D   = (unsigned short*)ws;
    unsigned short* w2r = D + 16384;

    if (blockIdx.x == 0) {
        ((u32x4*)D)[t]        = (u32x4){0u, 0u, 0u, 0u};
        ((u32x4*)D)[t + 1024] = (u32x4){0u, 0u, 0u, 0u};
        __syncthreads();

        if (t < CH) {
            const int c = t;
            float r[8];
            float nn = 0.f;
            #pragma unroll
            for (int i = 0; i < 8; ++i) { r[i] = rotor[c * 8 + i]; nn += r[i] * r[i]; }
            const float inv = rsqrtf(nn + 1e-6f);
            #pragma unroll
            for (int i = 0; i < 8; ++i) r[i] *= inv;

            const float REVv[8] = {1.f, 1.f, 1.f, -1.f, 1.f, -1.f, -1.f, -1.f};
            float rr[8];
            #pragma unroll
            for (int j = 0; j < 8; ++j) rr[j] = r[j] * REVv[j];

            float L[8][8], R[8][8];
            #pragma unroll
            for (int a = 0; a < 8; ++a)
                #pragma unroll
                for (int b = 0; b < 8; ++b) { L[a][b] = 0.f; R[a][b] = 0.f; }

            #pragma unroll
            for (int i = 0; i < 8; ++i)
                #pragma unroll
                for (int j = 0; j < 8; ++j) {
                    const float s = csign(i, j);
                    L[i ^ j][j] += r[i] * s;
                    R[i ^ j][i] += rr[j] * s;
                }

            const float sc = ln_scale[c];
            #pragma unroll
            for (int k = 0; k < 8; ++k)
                #pragma unroll
                for (int m = 0; m < 8; ++m) {
                    float acc = 0.f;
                    #pragma unroll
                    for (int i = 0; i < 8; ++i) acc += R[k][i] * L[i][m];
                    D[(c * 8 + k) * ROW + (c * 8 + m)] = f2bf(acc * sc);
                }
        }
    } else {
        #pragma unroll
        for (int task = t; task < ROW * CH; task += 1024) {
            const int outf = task >> 4;
            const int ci   = task & 15;
            const int kb = outf & 7, o = outf >> 3;
            const float4 w0 = *(const float4*)(w + (o * CH + ci) * 8);
            const float4 w1 = *(const float4*)(w + (o * CH + ci) * 8 + 4);
            const float wv[8] = {w0.x, w0.y, w0.z, w0.w, w1.x, w1.y, w1.z, w1.w};
            bf16x8 pk;
            #pragma unroll
            for (int j = 0; j < 8; ++j) {
                const int i = kb ^ j;
                pk[j] = (short)f2bf(wv[i] * csign(i, j));
            }
            *(bf16x8*)(w2r + outf * ROW + ci * 8) = pk;
        }
    }
}

// ---------------------------------------------------------------------------
// Fused kernel helpers
// ---------------------------------------------------------------------------

// LN -> rotor-sandwich MFMA (block-diag D) -> GELU -> swizzled bf16 sG write
__device__ __forceinline__ void phase1_mv(const float4 a, const float4 b,
                                          const bf16x8* Df, unsigned short* sG,
                                          int wave, int lcol, int lkg, int rt) {
    const float nn = a.x*a.x + a.y*a.y + a.z*a.z + a.w*a.w
                   + b.x*b.x + b.y*b.y + b.z*b.z + b.w*b.w;
    const float inv = rsqrtf(nn + 1e-6f);
    bf16x8 af;
    af[0] = (short)f2bf(a.x * inv); af[1] = (short)f2bf(a.y * inv);
    af[2] = (short)f2bf(a.z * inv); af[3] = (short)f2bf(a.w * inv);
    af[4] = (short)f2bf(b.x * inv); af[5] = (short)f2bf(b.y * inv);
    af[6] = (short)f2bf(b.z * inv); af[7] = (short)f2bf(b.w * inv);

    f32x4 p0 = (f32x4){0.f, 0.f, 0.f, 0.f};
    f32x4 p1 = (f32x4){0.f, 0.f, 0.f, 0.f};
    p0 = __builtin_amdgcn_mfma_f32_16x16x32_bf16(af, Df[0], p0, 0, 0, 0);
    p1 = __builtin_amdgcn_mfma_f32_16x16x32_bf16(af, Df[1], p1, 0, 0, 0);

    #pragma unroll
    for (int ctl = 0; ctl < 2; ++ctl) {
        const f32x4 p = ctl ? p1 : p0;
        const int colg = (2 * wave + ctl) * 16 + lcol;
        #pragma unroll
        for (int j = 0; j < 4; ++j) {
            const float y = gelu_poly(p[j]);
            const int row   = rt * 16 + lkg * 4 + j;
            const int chunk = (colg >> 3) ^ (row & 15);
            sG[row * ROW + chunk * 8 + (colg & 7)] = f2bf(y);
        }
    }
}

// 64x32 output sub-tile per wave: g(sG) @ W2R^T
__device__ __forceinline__ void gemm_tile(const unsigned short* sG,
                                          const bf16x8 Bf[2][4],
                                          f32x4 (&acc)[4][2], int lcol, int lkg) {
    #pragma unroll
    for (int rt = 0; rt < 4; ++rt)
        #pragma unroll
        for (int ct = 0; ct < 2; ++ct)
            acc[rt][ct] = (f32x4){0.f, 0.f, 0.f, 0.f};

    #pragma unroll
    for (int rt = 0; rt < 4; ++rt) {
        const int row = rt * 16 + lcol;
        #pragma unroll
        for (int ks = 0; ks < 4; ++ks) {
            const int chunk = (ks * 4 + lkg) ^ (row & 15);
            const bf16x8 afr = *(const bf16x8*)(sG + row * ROW + chunk * 8);
            acc[rt][0] = __builtin_amdgcn_mfma_f32_16x16x32_bf16(
                             afr, Bf[0][ks], acc[rt][0], 0, 0, 0);
            acc[rt][1] = __builtin_amdgcn_mfma_f32_16x16x32_bf16(
                             afr, Bf[1][ks], acc[rt][1], 0, 0, 0);
        }
    }
}

// nontemporal stores: out is write-once/never-re-read; bypass L2
// write-allocate + partial-line dirty eviction (R9 evidence: WRITE 90->75,
// FETCH 45->33 MB). ct innermost so 64B halves of a 128B line are adjacent.
__device__ __forceinline__ void store_tile(float* out, size_t trow0,
                                           const f32x4 (&acc)[4][2],
                                           int colb, int lcol, int lkg,
                                           const float bv[2]) {
    #pragma unroll
    for (int rt = 0; rt < 4; ++rt) {
        const size_t rbase = trow0 + rt * 16 + lkg * 4;
        #pragma unroll
        for (int j = 0; j < 4; ++j) {
            #pragma unroll
            for (int ct = 0; ct < 2; ++ct) {
                const int col = colb + ct * 16 + lcol;
                __builtin_nontemporal_store(acc[rt][ct][j] + bv[ct],
                                            out + (rbase + j) * ROW + col);
            }
        }
    }
}

// ---------------------------------------------------------------------------
// Fused: R7 geometry (best measured: 34.8us) + NT stores. 2 x 64-row tiles
// per block, both x tiles register-prefetched at block start (issue order
// xa0 -> Df/Bf -> xa1 so counted vmcnt never drains the prefetch). sG
// ping-pong -> ONE barrier per tile. grid = 1024. launch_bounds(256,4):
// R3+R8 lesson (twice burned): never force >4 waves/EU -- allocator spills.
// ---------------------------------------------------------------------------
__global__ __launch_bounds__(BLK, 4) void fused_kernel(
        const float* __restrict__ x,
        const float* __restrict__ bias,
        const float* __restrict__ ws,
        float* __restrict__ out)
{
    __shared__ unsigned short sG[2][TILE_ROWS * ROW];   // 2 x 16 KiB

    const int t    = threadIdx.x;
    const int lane = t & 63;
    const int wave = t >> 6;
    const int lcol = lane & 15;
    const int lkg  = lane >> 4;
    const int c    = 4 * wave + lkg;

    const unsigned short* D   = (const unsigned short*)ws;
    const unsigned short* w2r = D + 16384;

    const size_t row0 = (size_t)blockIdx.x * (TPB * TILE_ROWS);

    // ---- tile0 x -> regs (oldest in vmcnt FIFO)
    float4 xa0[4], xb0[4];
    #pragma unroll
    for (int rt = 0; rt < 4; ++rt) {
        const float4* xp = (const float4*)(x + ((row0 + rt * 16 + lcol) * CH + c) * DIM);
        xa0[rt] = xp[0];
        xb0[rt] = xp[1];
    }

    // ---- D / W2R fragments + bias (issued before tile1 prefetch)
    bf16x8 Df[2];
    #pragma unroll
    for (int ctl = 0; ctl < 2; ++ctl) {
        const int col = (2 * wave + ctl) * 16 + lcol;
        Df[ctl] = *(const bf16x8*)(D + col * ROW + 32 * wave + lkg * 8);
    }
    const int colb = wave * 32;
    bf16x8 Bf[2][4];
    #pragma unroll
    for (int ct = 0; ct < 2; ++ct)
        #pragma unroll
        for (int ks = 0; ks < 4; ++ks) {
            const int col = colb + ct * 16 + lcol;
            Bf[ct][ks] = *(const bf16x8*)(w2r + col * ROW + ks * 32 + lkg * 8);
        }
    float bv[2];
    bv[0] = bias[colb + lcol];
    bv[1] = bias[colb + 16 + lcol];

    // ---- tile1 x -> regs (newest; stays in flight through tile0 compute)
    float4 xa1[4], xb1[4];
    #pragma unroll
    for (int rt = 0; rt < 4; ++rt) {
        const float4* xp = (const float4*)(x + ((row0 + TILE_ROWS + rt * 16 + lcol) * CH + c) * DIM);
        xa1[rt] = xp[0];
        xb1[rt] = xp[1];
    }

    // ---- tile 0
    #pragma unroll
    for (int rt = 0; rt < 4; ++rt)
        phase1_mv(xa0[rt], xb0[rt], Df, sG[0], wave, lcol, lkg, rt);

    barrier_lgkm();                       // sG[0] visible; tile1 loads in flight

    f32x4 acc[4][2];
    gemm_tile(sG[0], Bf, acc, lcol, lkg);
    store_tile(out, row0, acc, colb, lcol, lkg, bv);

    // ---- tile 1 (writes sG[1]: no barrier needed against sG[0] readers)
    #pragma unroll
    for (int rt = 0; rt < 4; ++rt)
        phase1_mv(xa1[rt], xb1[rt], Df, sG[1], wave, lcol, lkg, rt);

    barrier_lgkm();

    gemm_tile(sG[1], Bf, acc, lcol, lkg);
    store_tile(out, row0 + TILE_ROWS, acc, colb, lcol, lkg, bv);
}

extern "C" void kernel_launch(void* const* d_in, const int* in_sizes, int n_in,
                              void* d_out, int out_size, void* d_ws, size_t ws_size,
                              hipStream_t stream)
{
    const float* x        = (const float*)d_in[0];
    const float* ln_scale = (const float*)d_in[1];
    const float* rotor    = (const float*)d_in[2];
    const float* w        = (const float*)d_in[3];
    const float* bias     = (const float*)d_in[4];
    float* out = (float*)d_out;
    float* ws  = (float*)d_ws;

    precompute_kernel<<<dim3(2), dim3(1024), 0, stream>>>(rotor, w, ln_scale, ws);

    const int nrows   = in_sizes[0] / (CH * DIM);          // 131072
    const int nblocks = nrows / (TPB * TILE_ROWS);         // 1024

    fused_kernel<<<dim3(nblocks), dim3(BLK), 0, stream>>>(x, bias, ws, out);
}

// Round 12
// 36.989 us; speedup vs baseline: 1.6359x; 1.0329x over previous
//
#include <hip/hip_runtime.h>
#include <math.h>
#include <stdint.h>

#define CH 16
#define DIM 8
#define ROW 128            // CH*DIM
#define TILE_ROWS 64
#define BLK 256            // 4 waves

typedef __attribute__((ext_vector_type(8))) short bf16x8;
typedef __attribute__((ext_vector_type(4))) float f32x4;
typedef __attribute__((ext_vector_type(4))) unsigned int u32x4;

// Cayley sign for Cl(3,0): e_a * e_b = csign(a,b) * e_{a^b}
__device__ __forceinline__ float csign(int a, int b) {
    int s = 0;
    int aa = a >> 1;
    while (aa) { s ^= (__popc(aa & b) & 1); aa >>= 1; }
    return s ? -1.0f : 1.0f;
}

// float -> bf16 (round-to-nearest-even)
__device__ __forceinline__ unsigned short f2bf(float f) {
    union { float f; unsigned u; } x; x.f = f;
    unsigned r = x.u + 0x7FFF + ((x.u >> 16) & 1);
    return (unsigned short)(r >> 16);
}

// Exact-GELU via odd Taylor poly for erf (|s|<=~1.02 after unit-norm rotor
// sandwich, ln_scale folded into D; poly err < 2e-6 on that domain).
__device__ __forceinline__ float gelu_poly(float s) {
    const float z = s * 0.70710678f;
    const float u = z * z;
    float p = -8.5483270e-04f;
    p = fmaf(p, u,  5.2239776e-03f);
    p = fmaf(p, u, -2.6866138e-02f);
    p = fmaf(p, u,  1.1283792e-01f);
    p = fmaf(p, u, -3.7612639e-01f);
    p = fmaf(p, u,  1.1283792e+00f);
    return 0.5f * s * fmaf(z, p, 1.0f);
}

// barrier draining only LDS ordering (keeps global loads/stores in flight)
__device__ __forceinline__ void barrier_lgkm() {
    asm volatile("s_waitcnt lgkmcnt(0)" ::: "memory");
    __builtin_amdgcn_s_barrier();
    __builtin_amdgcn_sched_barrier(0);
}

// ---------------------------------------------------------------------------
// Precompute, grid=2 x 1024 threads:
//   block 0: D[f_out][f_in] bf16 block-diag rotor-sandwich (ln_scale folded)
//   block 1: W2R[out_f][in_f] bf16 128x128 CliffordLinear matrix
// ws as ushort*: u[0..16384) = D, u[16384..32768) = W2R
// ---------------------------------------------------------------------------
__global__ void precompute_kernel(const float* __restrict__ rotor,
                                  const float* __restrict__ w,
                                  const float* __restrict__ ln_scale,
                                  float* __restrict__ ws)
{
    const int t = threadIdx.x;
    unsigned short* D   = (unsigned short*)ws;
    unsigned short* w2r = D + 16384;

    if (blockIdx.x == 0) {
        ((u32x4*)D)[t]        = (u32x4){0u, 0u, 0u, 0u};
        ((u32x4*)D)[t + 1024] = (u32x4){0u, 0u, 0u, 0u};
        __syncthreads();

        if (t < CH) {
            const int c = t;
            float r[8];
            float nn = 0.f;
            #pragma unroll
            for (int i = 0; i < 8; ++i) { r[i] = rotor[c * 8 + i]; nn += r[i] * r[i]; }
            const float inv = rsqrtf(nn + 1e-6f);
            #pragma unroll
            for (int i = 0; i < 8; ++i) r[i] *= inv;

            const float REVv[8] = {1.f, 1.f, 1.f, -1.f, 1.f, -1.f, -1.f, -1.f};
            float rr[8];
            #pragma unroll
            for (int j = 0; j < 8; ++j) rr[j] = r[j] * REVv[j];

            float L[8][8], R[8][8];
            #pragma unroll
            for (int a = 0; a < 8; ++a)
                #pragma unroll
                for (int b = 0; b < 8; ++b) { L[a][b] = 0.f; R[a][b] = 0.f; }

            #pragma unroll
            for (int i = 0; i < 8; ++i)
                #pragma unroll
                for (int j = 0; j < 8; ++j) {
                    const float s = csign(i, j);
                    L[i ^ j][j] += r[i] * s;
                    R[i ^ j][i] += rr[j] * s;
                }

            const float sc = ln_scale[c];
            #pragma unroll
            for (int k = 0; k < 8; ++k)
                #pragma unroll
                for (int m = 0; m < 8; ++m) {
                    float acc = 0.f;
                    #pragma unroll
                    for (int i = 0; i < 8; ++i) acc += R[k][i] * L[i][m];
                    D[(c * 8 + k) * ROW + (c * 8 + m)] = f2bf(acc * sc);
                }
        }
    } else {
        #pragma unroll
        for (int task = t; task < ROW * CH; task += 1024) {
            const int outf = task >> 4;
            const int ci   = task & 15;
            const int kb = outf & 7, o = outf >> 3;
            const float4 w0 = *(const float4*)(w + (o * CH + ci) * 8);
            const float4 w1 = *(const float4*)(w + (o * CH + ci) * 8 + 4);
            const float wv[8] = {w0.x, w0.y, w0.z, w0.w, w1.x, w1.y, w1.z, w1.w};
            bf16x8 pk;
            #pragma unroll
            for (int j = 0; j < 8; ++j) {
                const int i = kb ^ j;
                pk[j] = (short)f2bf(wv[i] * csign(i, j));
            }
            *(bf16x8*)(w2r + outf * ROW + ci * 8) = pk;
        }
    }
}

// ---------------------------------------------------------------------------
// Fused kernel helpers
// ---------------------------------------------------------------------------

// LN -> rotor-sandwich MFMA (block-diag D) -> GELU -> swizzled bf16 sG write
__device__ __forceinline__ void phase1_mv(const float4 a, const float4 b,
                                          const bf16x8* Df, unsigned short* sG,
                                          int wave, int lcol, int lkg, int rt) {
    const float nn = a.x*a.x + a.y*a.y + a.z*a.z + a.w*a.w
                   + b.x*b.x + b.y*b.y + b.z*b.z + b.w*b.w;
    const float inv = rsqrtf(nn + 1e-6f);
    bf16x8 af;
    af[0] = (short)f2bf(a.x * inv); af[1] = (short)f2bf(a.y * inv);
    af[2] = (short)f2bf(a.z * inv); af[3] = (short)f2bf(a.w * inv);
    af[4] = (short)f2bf(b.x * inv); af[5] = (short)f2bf(b.y * inv);
    af[6] = (short)f2bf(b.z * inv); af[7] = (short)f2bf(b.w * inv);

    f32x4 p0 = (f32x4){0.f, 0.f, 0.f, 0.f};
    f32x4 p1 = (f32x4){0.f, 0.f, 0.f, 0.f};
    p0 = __builtin_amdgcn_mfma_f32_16x16x32_bf16(af, Df[0], p0, 0, 0, 0);
    p1 = __builtin_amdgcn_mfma_f32_16x16x32_bf16(af, Df[1], p1, 0, 0, 0);

    #pragma unroll
    for (int ctl = 0; ctl < 2; ++ctl) {
        const f32x4 p = ctl ? p1 : p0;
        const int colg = (2 * wave + ctl) * 16 + lcol;
        #pragma unroll
        for (int j = 0; j < 4; ++j) {
            const float y = gelu_poly(p[j]);
            const int row   = rt * 16 + lkg * 4 + j;
            const int chunk = (colg >> 3) ^ (row & 15);
            sG[row * ROW + chunk * 8 + (colg & 7)] = f2bf(y);
        }
    }
}

// ---------------------------------------------------------------------------
// Fused: ONE 64-row tile per block, grid = 2048. Occupancy play (R11 PMC:
// 29% occupancy, VALU 23%, MFMA 4.7%, nothing saturated => latency-bound):
// smaller block state (no tile1 prefetch regs) + 16 KiB LDS + 2048 blocks
// lets 5-8 blocks/CU stay resident; cross-block TLP replaces the intra-block
// pipeline. Plain stores (NT regressed: R11 34.8->38.2). Bf/bias issued
// after phase1, before the single barrier: lower phase-1 VGPR peak, latency
// hidden behind barrier wait. launch_bounds(256,4) only (R3/R8: never force
// higher -- allocator spills).
// ---------------------------------------------------------------------------
__global__ __launch_bounds__(BLK, 4) void fused_kernel(
        const float* __restrict__ x,
        const float* __restrict__ bias,
        const float* __restrict__ ws,
        float* __restrict__ out)
{
    __shared__ unsigned short sG[TILE_ROWS * ROW];   // 16 KiB

    const int t    = threadIdx.x;
    const int lane = t & 63;
    const int wave = t >> 6;
    const int lcol = lane & 15;
    const int lkg  = lane >> 4;
    const int c    = 4 * wave + lkg;

    const unsigned short* D   = (const unsigned short*)ws;
    const unsigned short* w2r = D + 16384;

    const size_t row0 = (size_t)blockIdx.x * TILE_ROWS;

    // ---- x tile -> regs
    float4 xa[4], xb[4];
    #pragma unroll
    for (int rt = 0; rt < 4; ++rt) {
        const float4* xp = (const float4*)(x + ((row0 + rt * 16 + lcol) * CH + c) * DIM);
        xa[rt] = xp[0];
        xb[rt] = xp[1];
    }

    // ---- D fragments (needed by phase1)
    bf16x8 Df[2];
    #pragma unroll
    for (int ctl = 0; ctl < 2; ++ctl) {
        const int col = (2 * wave + ctl) * 16 + lcol;
        Df[ctl] = *(const bf16x8*)(D + col * ROW + 32 * wave + lkg * 8);
    }

    // ---- phase 1: LN -> rotor MFMA -> GELU -> sG
    #pragma unroll
    for (int rt = 0; rt < 4; ++rt)
        phase1_mv(xa[rt], xb[rt], Df, sG, wave, lcol, lkg, rt);

    // ---- W2R fragments + bias: issue AFTER phase1 (lower phase-1 VGPR
    // peak), BEFORE the barrier (latency hides under the barrier wait)
    const int colb = wave * 32;
    bf16x8 Bf[2][4];
    #pragma unroll
    for (int ct = 0; ct < 2; ++ct)
        #pragma unroll
        for (int ks = 0; ks < 4; ++ks) {
            const int col = colb + ct * 16 + lcol;
            Bf[ct][ks] = *(const bf16x8*)(w2r + col * ROW + ks * 32 + lkg * 8);
        }
    float bv[2];
    bv[0] = bias[colb + lcol];
    bv[1] = bias[colb + 16 + lcol];

    barrier_lgkm();      // sG visible; Bf/bias loads still in flight

    // ---- phase 2: MFMA GEMM, each wave 64 rows x 32 cols
    f32x4 acc[4][2];
    #pragma unroll
    for (int rt = 0; rt < 4; ++rt)
        #pragma unroll
        for (int ct = 0; ct < 2; ++ct)
            acc[rt][ct] = (f32x4){0.f, 0.f, 0.f, 0.f};

    #pragma unroll
    for (int rt = 0; rt < 4; ++rt) {
        const int row = rt * 16 + lcol;
        #pragma unroll
        for (int ks = 0; ks < 4; ++ks) {
            const int chunk = (ks * 4 + lkg) ^ (row & 15);
            const bf16x8 afr = *(const bf16x8*)(sG + row * ROW + chunk * 8);
            acc[rt][0] = __builtin_amdgcn_mfma_f32_16x16x32_bf16(
                             afr, Bf[0][ks], acc[rt][0], 0, 0, 0);
            acc[rt][1] = __builtin_amdgcn_mfma_f32_16x16x32_bf16(
                             afr, Bf[1][ks], acc[rt][1], 0, 0, 0);
        }
    }

    // ---- epilogue: plain coalesced stores (ct innermost: both 64B halves
    // of each 128B line back-to-back)
    #pragma unroll
    for (int rt = 0; rt < 4; ++rt) {
        const size_t rbase = row0 + rt * 16 + lkg * 4;
        #pragma unroll
        for (int j = 0; j < 4; ++j) {
            #pragma unroll
            for (int ct = 0; ct < 2; ++ct) {
                const int col = colb + ct * 16 + lcol;
                out[(rbase + j) * ROW + col] = acc[rt][ct][j] + bv[ct];
            }
        }
    }
}

extern "C" void kernel_launch(void* const* d_in, const int* in_sizes, int n_in,
                              void* d_out, int out_size, void* d_ws, size_t ws_size,
                              hipStream_t stream)
{
    const float* x        = (const float*)d_in[0];
    const float* ln_scale = (const float*)d_in[1];
    const float* rotor    = (const float*)d_in[2];
    const float* w        = (const float*)d_in[3];
    const float* bias     = (const float*)d_in[4];
    float* out = (float*)d_out;
    float* ws  = (float*)d_ws;

    precompute_kernel<<<dim3(2), dim3(1024), 0, stream>>>(rotor, w, ln_scale, ws);

    const int nrows   = in_sizes[0] / (CH * DIM);          // 131072
    const int nblocks = nrows / TILE_ROWS;                 // 2048

    fused_kernel<<<dim3(nblocks), dim3(BLK), 0, stream>>>(x, bias, ws, out);
}